// Round 1
// baseline (316.127 us; speedup 1.0000x reference)
//
#include <hip/hip_runtime.h>
#include <math.h>

// Gaussian NLL + analytic grad + Hessian wrt (mu, pre-softplus-std).
// Memory-bound elementwise: 40 B/elem -> ~335 MB @ N=2^23 -> ~53 us floor.

__global__ __launch_bounds__(256) void unll_kernel(
    const float4* __restrict__ yp,   // y_pred as float4 pairs: (mu0,s0,mu1,s1)
    const float4* __restrict__ yt,   // y_true as float4
    float4* __restrict__ out_loss,   // N floats
    float4* __restrict__ out_g,      // 2N floats
    float4* __restrict__ out_h,      // 4N floats
    int nvec)                        // N/4
{
    int idx = blockIdx.x * blockDim.x + threadIdx.x;
    if (idx >= nvec) return;

    float4 a = yp[2 * idx];      // mu0 s0 mu1 s1
    float4 b = yp[2 * idx + 1];  // mu2 s2 mu3 s3
    float4 t = yt[idx];          // y0 y1 y2 y3

    float mu[4] = {a.x, a.z, b.x, b.z};
    float ss[4] = {a.y, a.w, b.y, b.w};
    float yy[4] = {t.x, t.y, t.z, t.w};

    float L[4], G0[4], G1[4], H00[4], H01[4], H11[4];

#pragma unroll
    for (int k = 0; k < 4; ++k) {
        float s = ss[k];
        // stable softplus: max(s,0) + log1p(exp(-|s|))
        float stdv = fmaxf(s, 0.0f) + log1pf(expf(-fabsf(s)));
        float sig  = 1.0f / (1.0f + expf(-s));
        float inv  = 1.0f / stdv;
        float z    = (yy[k] - mu[k]) * inv;
        float z2   = z * z;

        L[k]  = 0.5f * z2 + logf(stdv) + 0.91893853320467274178f; // 0.5*log(2*pi)
        G0[k] = -z * inv;
        G1[k] = sig * (1.0f - z2) * inv;

        float inv2 = inv * inv;
        H00[k] = inv2;
        H01[k] = 2.0f * z * sig * inv2;
        H11[k] = sig * (1.0f - sig) * (1.0f - z2) * inv
               + sig * sig * (3.0f * z2 - 1.0f) * inv2;
    }

    out_loss[idx] = make_float4(L[0], L[1], L[2], L[3]);

    out_g[2 * idx]     = make_float4(G0[0], G1[0], G0[1], G1[1]);
    out_g[2 * idx + 1] = make_float4(G0[2], G1[2], G0[3], G1[3]);

#pragma unroll
    for (int k = 0; k < 4; ++k) {
        out_h[4 * idx + k] = make_float4(H00[k], H01[k], H01[k], H11[k]);
    }
}

extern "C" void kernel_launch(void* const* d_in, const int* in_sizes, int n_in,
                              void* d_out, int out_size, void* d_ws, size_t ws_size,
                              hipStream_t stream) {
    const float* y_pred = (const float*)d_in[0];  // [N,2]
    const float* y_true = (const float*)d_in[1];  // [N]
    float* out = (float*)d_out;                   // loss[N] | d[N*2] | dd[N*4]

    const int N = in_sizes[1];
    const int nvec = N / 4;  // N = 2^23, divisible by 4

    float4* out_loss = (float4*)out;
    float4* out_g    = (float4*)(out + (size_t)N);
    float4* out_h    = (float4*)(out + (size_t)3 * N);

    const int block = 256;
    const int grid = (nvec + block - 1) / block;
    unll_kernel<<<grid, block, 0, stream>>>(
        (const float4*)y_pred, (const float4*)y_true,
        out_loss, out_g, out_h, nvec);
}

// Round 2
// 294.761 us; speedup vs baseline: 1.0725x; 1.0725x over previous
//
#include <hip/hip_runtime.h>
#include <math.h>

// Gaussian NLL + analytic grad + Hessian wrt (mu, pre-softplus-std).
// One element per thread: every global access is stride-1 coalesced.
//   loads : y_pred float2 (8 B/lane), y_true float (4 B/lane)
//   stores: loss dword, d_loss dwordx2, dd_loss dwordx4
// Traffic = 40 B/elem * 2^23 = 335 MB -> ~53 us @ 6.3 TB/s.

__global__ __launch_bounds__(256) void unll_kernel(
    const float2* __restrict__ yp,   // [N] of (mu, s)
    const float*  __restrict__ yt,   // [N]
    float*  __restrict__ out_loss,   // [N]
    float2* __restrict__ out_g,      // [N] of (g_mu, g_s)
    float4* __restrict__ out_h,      // [N] of (h00, h01, h10, h11)
    int n)
{
    int i = blockIdx.x * blockDim.x + threadIdx.x;
    if (i >= n) return;

    float2 p = yp[i];
    float  y = yt[i];

    float mu = p.x;
    float s  = p.y;

    // stable softplus: max(s,0) + log1p(exp(-|s|))
    float e    = __expf(-fabsf(s));
    float stdv = fmaxf(s, 0.0f) + __logf(1.0f + e);
    float sig  = 1.0f / (1.0f + __expf(-s));
    float inv  = 1.0f / stdv;
    float z    = (y - mu) * inv;
    float z2   = z * z;

    float L  = 0.5f * z2 + __logf(stdv) + 0.91893853320467274178f; // 0.5*log(2*pi)
    float g0 = -z * inv;
    float g1 = sig * (1.0f - z2) * inv;

    float inv2 = inv * inv;
    float h00 = inv2;
    float h01 = 2.0f * z * sig * inv2;
    float h11 = sig * (1.0f - sig) * (1.0f - z2) * inv
              + sig * sig * (3.0f * z2 - 1.0f) * inv2;

    out_loss[i] = L;
    out_g[i]    = make_float2(g0, g1);
    out_h[i]    = make_float4(h00, h01, h01, h11);
}

extern "C" void kernel_launch(void* const* d_in, const int* in_sizes, int n_in,
                              void* d_out, int out_size, void* d_ws, size_t ws_size,
                              hipStream_t stream) {
    const float* y_pred = (const float*)d_in[0];  // [N,2]
    const float* y_true = (const float*)d_in[1];  // [N]
    float* out = (float*)d_out;                   // loss[N] | d[2N] | dd[4N]

    const int N = in_sizes[1];

    float*  out_loss = out;
    float2* out_g    = (float2*)(out + (size_t)N);
    float4* out_h    = (float4*)(out + (size_t)3 * N);

    const int block = 256;
    const int grid = (N + block - 1) / block;
    unll_kernel<<<grid, block, 0, stream>>>(
        (const float2*)y_pred, y_true, out_loss, out_g, out_h, N);
}